// Round 14
// baseline (300.908 us; speedup 1.0000x reference)
//
#include <hip/hip_runtime.h>
#include <stdint.h>

// Problem constants
#define B_SZ 2
#define T_SEQ 2048
#define DM 2048
#define NH 32
#define NKV 8
#define HD 64
#define QKV_W 3072

typedef unsigned short u16;
typedef __bf16 bf16x8 __attribute__((ext_vector_type(8)));
typedef float floatx4 __attribute__((ext_vector_type(4)));

__device__ __forceinline__ float bf2f(u16 u) {
  union { unsigned u; float f; } v; v.u = ((unsigned)u) << 16; return v.f;
}
__device__ __forceinline__ u16 f2bf(float f) {
  union { float f; unsigned u; } v; v.f = f;
  unsigned r = v.u + 0x7fff + ((v.u >> 16) & 1);   // RNE
  return (u16)(r >> 16);
}
// pack 2 f32 -> 2 bf16 (truncation) in one v_perm
__device__ __forceinline__ unsigned pk2bf(float hi, float lo) {
  return __builtin_amdgcn_perm(__float_as_uint(hi), __float_as_uint(lo), 0x07060302u);
}
__device__ __forceinline__ float fexp2(float x) {
#if __has_builtin(__builtin_amdgcn_exp2f)
  return __builtin_amdgcn_exp2f(x);
#else
  return exp2f(x);
#endif
}

__device__ __forceinline__ void gld_lds16(const void* g, void* l) {
  __builtin_amdgcn_global_load_lds(
      (const __attribute__((address_space(1))) unsigned int*)g,
      (__attribute__((address_space(3))) unsigned int*)l, 16, 0, 0);
}

// ---------------------------------------------------------------------------
// f32 -> bf16 conversion (RNE), vectorized float4 -> ushort4, grid-stride.
// ---------------------------------------------------------------------------
__global__ __launch_bounds__(256) void conv_kernel(
    const float* __restrict__ src, u16* __restrict__ dst, int n4)
{
  int i = blockIdx.x * 256 + threadIdx.x;
  int stride = gridDim.x * 256;
  for (; i < n4; i += stride) {
    float4 v = ((const float4*)src)[i];
    ushort4 o;
    o.x = f2bf(v.x); o.y = f2bf(v.y); o.z = f2bf(v.z); o.w = f2bf(v.w);
    ((ushort4*)dst)[i] = o;
  }
}

// ---------------------------------------------------------------------------
// Fused Wq/Wk/Wv f32->bf16 conversion. dst regions in wqkvb are contiguous.
// (Round-10's further merge with the x conv regressed ~6us — keep split.)
// ---------------------------------------------------------------------------
__global__ __launch_bounds__(256) void conv_wqkv_kernel(
    const float* __restrict__ Wq, const float* __restrict__ Wk,
    const float* __restrict__ Wv, u16* __restrict__ dst)
{
  int i = blockIdx.x * 256 + threadIdx.x;
  int stride = gridDim.x * 256;
  for (; i < 1572864; i += stride) {
    float4 v;
    if (i < 1048576)      v = ((const float4*)Wq)[i];
    else if (i < 1310720) v = ((const float4*)Wk)[i - 1048576];
    else                  v = ((const float4*)Wv)[i - 1310720];
    ushort4 o;
    o.x = f2bf(v.x); o.y = f2bf(v.y); o.z = f2bf(v.z); o.w = f2bf(v.w);
    ((ushort4*)dst)[i] = o;
  }
}

// ---------------------------------------------------------------------------
// GEMM1: qkv[4096,3072](bf16) = xb[4096,2048](bf16) @ wqkvb[3072,2048]^T
// PREFETCH double-buffer, STATIC unroll-2, full-drain barriers:
//   stage(buf^1, t+1) at iteration TOP -> 8 gld_lds fly across the whole
//   compute phase; __syncthreads() at iteration end (full vmcnt/lgkmcnt
//   drain) -> sync strength identical to the 4x-proven two-barrier loop,
//   deterministic by construction. Unroll-2 makes buf0/buf1 compile-time
//   (round-5 lesson: cur-indexed addressing doubled VALUBusy).
// BK=64, chunk-XOR swizzled LDS (0 bank conflicts, verified r9).
// LDS 64 KB -> 2 blocks/CU (tripwire: m132-style occupancy cliff => revert).
// Round-9: no fused epilogues (VGPR 68->116 killed occupancy).
// ---------------------------------------------------------------------------
__global__ __launch_bounds__(256) void gemm_qkv_kernel(
    const u16* __restrict__ A, const u16* __restrict__ Bt,
    u16* __restrict__ C)
{
  __shared__ __align__(16) u16 sA[2][128 * 64];   // 32 KB
  __shared__ __align__(16) u16 sB[2][128 * 64];   // 32 KB

  const int n0 = blockIdx.x * 128;
  const int m0 = blockIdx.y * 128;
  const int K = 2048;

  const int tid  = threadIdx.x;
  const int lane = tid & 63;
  const int w    = tid >> 6;
  const int wm = w >> 1, wn = w & 1;
  const int lm = lane & 15, lq = lane >> 4;

  floatx4 acc[4][4];
  #pragma unroll
  for (int i = 0; i < 4; i++)
    #pragma unroll
    for (int j = 0; j < 4; j++) { floatx4 z = {0.f,0.f,0.f,0.f}; acc[i][j] = z; }

  // staging: pass p covers rows p*32 + (tid>>3); chunk = (tid&7)^((tid>>3)&7)
  const int srow   = tid >> 3;
  const int schunk = (tid & 7) ^ (srow & 7);
  const u16* ApG = A  + (size_t)(m0 + srow) * K + schunk * 8;
  const u16* BpG = Bt + (size_t)(n0 + srow) * K + schunk * 8;
  u16* sAd0 = sA[0] + tid * 8;  u16* sAd1 = sA[1] + tid * 8;
  u16* sBd0 = sB[0] + tid * 8;  u16* sBd1 = sB[1] + tid * 8;

  // fragment read bases; slot (kk*4+lq)^sw holds global chunk kk*4+lq
  const int sw  = lm & 7;
  const int rba = (wm * 64 + lm) * 64;
  const int rbb = (wn * 64 + lm) * 64;
  const int c0  = (lq ^ sw) * 8;
  const int c1  = ((4 + lq) ^ sw) * 8;

  auto stage = [&](u16* sAd, u16* sBd, int k0) {
    #pragma unroll
    for (int p = 0; p < 4; p++) {
      gld_lds16(ApG + (size_t)p * 32 * K + k0, sAd + p * 2048);
      gld_lds16(BpG + (size_t)p * 32 * K + k0, sBd + p * 2048);
    }
  };
  auto compute = [&](const u16* sAc, const u16* sBc) {
    #pragma unroll
    for (int kk = 0; kk < 2; kk++) {
      const int ck = kk ? c1 : c0;
      bf16x8 af[4], bfr[4];
      #pragma unroll
      for (int mi = 0; mi < 4; mi++)
        af[mi] = *(const bf16x8*)(sAc + rba + mi * 1024 + ck);
      #pragma unroll
      for (int ni = 0; ni < 4; ni++)
        bfr[ni] = *(const bf16x8*)(sBc + rbb + ni * 1024 + ck);

      #pragma unroll
      for (int mi = 0; mi < 4; mi++)
        #pragma unroll
        for (int ni = 0; ni < 4; ni++)
          acc[mi][ni] = __builtin_amdgcn_mfma_f32_16x16x32_bf16(
              af[mi], bfr[ni], acc[mi][ni], 0, 0, 0);
    }
  };

  // prologue: tile 0 -> buf0
  stage(sAd0, sBd0, 0);
  __syncthreads();                       // buf0 ready

  for (int k0 = 0; k0 < K; k0 += 128) {  // 16 iters, 2 tiles each (static bufs)
    stage(sAd1, sBd1, k0 + 64);          // next tile flies during compute
    compute(sA[0], sB[0]);
    __syncthreads();                     // buf1 ready; buf0 reads done
    if (k0 + 128 < K) stage(sAd0, sBd0, k0 + 128);
    compute(sA[1], sB[1]);
    __syncthreads();                     // buf0 ready; buf1 reads done
  }

  #pragma unroll
  for (int mi = 0; mi < 4; mi++)
    #pragma unroll
    for (int ni = 0; ni < 4; ni++)
      #pragma unroll
      for (int r = 0; r < 4; r++) {
        int row = m0 + wm*64 + mi*16 + lq*4 + r;
        int col = n0 + wn*64 + ni*16 + lm;
        C[(size_t)row * QKV_W + col] = f2bf(acc[mi][ni][r]);
      }
}

// ---------------------------------------------------------------------------
// GEMM2: out[4096,2048](f32) = attn[4096,2048](bf16) @ wob[2048,2048]^T(bf16)
// Same prefetch-dbuf unroll-2 structure as GEMM1.
// ---------------------------------------------------------------------------
__global__ __launch_bounds__(256) void gemm_out_kernel(
    const u16* __restrict__ A, const u16* __restrict__ Bt,
    float* __restrict__ C)
{
  __shared__ __align__(16) u16 sA[2][128 * 64];
  __shared__ __align__(16) u16 sB[2][128 * 64];

  const int n0 = blockIdx.x * 128;
  const int m0 = blockIdx.y * 128;
  const int K = 2048;

  const int tid  = threadIdx.x;
  const int lane = tid & 63;
  const int w    = tid >> 6;
  const int wm = w >> 1, wn = w & 1;
  const int lm = lane & 15, lq = lane >> 4;

  floatx4 acc[4][4];
  #pragma unroll
  for (int i = 0; i < 4; i++)
    #pragma unroll
    for (int j = 0; j < 4; j++) { floatx4 z = {0.f,0.f,0.f,0.f}; acc[i][j] = z; }

  const int srow   = tid >> 3;
  const int schunk = (tid & 7) ^ (srow & 7);
  const u16* ApG = A  + (size_t)(m0 + srow) * K + schunk * 8;
  const u16* BpG = Bt + (size_t)(n0 + srow) * K + schunk * 8;
  u16* sAd0 = sA[0] + tid * 8;  u16* sAd1 = sA[1] + tid * 8;
  u16* sBd0 = sB[0] + tid * 8;  u16* sBd1 = sB[1] + tid * 8;

  const int sw  = lm & 7;
  const int rba = (wm * 64 + lm) * 64;
  const int rbb = (wn * 64 + lm) * 64;
  const int c0  = (lq ^ sw) * 8;
  const int c1  = ((4 + lq) ^ sw) * 8;

  auto stage = [&](u16* sAd, u16* sBd, int k0) {
    #pragma unroll
    for (int p = 0; p < 4; p++) {
      gld_lds16(ApG + (size_t)p * 32 * K + k0, sAd + p * 2048);
      gld_lds16(BpG + (size_t)p * 32 * K + k0, sBd + p * 2048);
    }
  };
  auto compute = [&](const u16* sAc, const u16* sBc) {
    #pragma unroll
    for (int kk = 0; kk < 2; kk++) {
      const int ck = kk ? c1 : c0;
      bf16x8 af[4], bfr[4];
      #pragma unroll
      for (int mi = 0; mi < 4; mi++)
        af[mi] = *(const bf16x8*)(sAc + rba + mi * 1024 + ck);
      #pragma unroll
      for (int ni = 0; ni < 4; ni++)
        bfr[ni] = *(const bf16x8*)(sBc + rbb + ni * 1024 + ck);

      #pragma unroll
      for (int mi = 0; mi < 4; mi++)
        #pragma unroll
        for (int ni = 0; ni < 4; ni++)
          acc[mi][ni] = __builtin_amdgcn_mfma_f32_16x16x32_bf16(
              af[mi], bfr[ni], acc[mi][ni], 0, 0, 0);
    }
  };

  stage(sAd0, sBd0, 0);
  __syncthreads();

  for (int k0 = 0; k0 < K; k0 += 128) {
    stage(sAd1, sBd1, k0 + 64);
    compute(sA[0], sB[0]);
    __syncthreads();
    if (k0 + 128 < K) stage(sAd0, sBd0, k0 + 128);
    compute(sA[1], sB[1]);
    __syncthreads();
  }

  #pragma unroll
  for (int mi = 0; mi < 4; mi++)
    #pragma unroll
    for (int ni = 0; ni < 4; ni++)
      #pragma unroll
      for (int r = 0; r < 4; r++) {
        int row = m0 + wm*64 + mi*16 + lq*4 + r;
        int col = n0 + wn*64 + ni*16 + lm;
        C[(size_t)row * DM + col] = acc[mi][ni][r];
      }
}

// ---------------------------------------------------------------------------
// Merged prep: RoPE (blocks 0..4095) + V transpose (blocks 4096..4607).
// Block-level concatenation — bodies byte-identical to the proven standalone
// kernels (round-10 lesson: don't interleave streams within a loop).
// ---------------------------------------------------------------------------
#define QSCALE 0.180336880f   // 0.125 * 1.44269504
__global__ __launch_bounds__(256) void prep_kernel(
    const u16* __restrict__ qkv, const float* __restrict__ cosf,
    const float* __restrict__ sinf, u16* __restrict__ qb,
    u16* __restrict__ kb, u16* __restrict__ vbt)
{
  __shared__ u16 tile[64][66];     // used by vtrans branch only
  const int tid = threadIdx.x;

  if (blockIdx.x < 4096) {
    // ---- RoPE ----
    const int bt = blockIdx.x;
    const int b = bt / T_SEQ, t = bt % T_SEQ;
    const u16* row = qkv + (size_t)bt * QKV_W;

    #pragma unroll
    for (int i = 0; i < 4; i++) {
      int idx = i * 256 + tid;          // 0..1023
      int h = idx >> 5, dp = idx & 31;
      float x1 = bf2f(row[h * 64 + dp]);
      float x2 = bf2f(row[h * 64 + dp + 32]);
      float c = cosf[t * 64 + dp];
      float s = sinf[t * 64 + dp];
      float o1 = (x1 * c - x2 * s) * QSCALE;
      float o2 = (x2 * c + x1 * s) * QSCALE;
      size_t base = ((size_t)(b * NH + h) * T_SEQ + t) * HD + dp;
      qb[base]      = f2bf(o1);
      qb[base + 32] = f2bf(o2);
    }
    {
      int idx = tid;                    // 0..255
      int kvh = idx >> 5, dp = idx & 31;
      float x1 = bf2f(row[2048 + kvh * 64 + dp]);
      float x2 = bf2f(row[2048 + kvh * 64 + dp + 32]);
      float c = cosf[t * 64 + dp];
      float s = sinf[t * 64 + dp];
      size_t base = ((size_t)(b * NKV + kvh) * T_SEQ + t) * HD + dp;
      kb[base]      = f2bf(x1 * c - x2 * s);
      kb[base + 32] = f2bf(x2 * c + x1 * s);
    }
  } else {
    // ---- V transpose: qkv cols [2560,3072) -> vbt (B,KV,64,T) ----
    const int idx2 = blockIdx.x - 4096;   // 0..511
    const int t0  = (idx2 & 31) * 64;
    const int kvh = (idx2 >> 5) & 7;
    const int b   = idx2 >> 8;

    #pragma unroll
    for (int i = 0; i < 16; i++) {
      int idx = i * 256 + tid;
      int r = idx >> 6, c = idx & 63;
      tile[r][c] = qkv[(size_t)(b * T_SEQ + t0 + r) * QKV_W + 2560 + kvh * 64 + c];
    }
    __syncthreads();
    #pragma unroll
    for (int i = 0; i < 16; i++) {
      int idx = i * 256 + tid;
      int d = idx >> 6, c = idx & 63;
      vbt[((size_t)(b * NKV + kvh) * HD + d) * T_SEQ + t0 + c] = tile[c][d];
    }
  }
}

// ---------------------------------------------------------------------------
// Flash attention v9 (GQA-fused, 32-row q-tiles, paired-tile staging,
// split-phase tile body — round-12, perf-neutral vs v8 but kept).
// Two-barrier sync template (deterministic; single-barrier dbuf retired r6).
// launch_bounds(256,3); defer-max (THR=8, log2); setprio around MFMA;
// 1024-block descending LPT grid. LDS ~42 KB -> 3 blocks/CU.
// ---------------------------------------------------------------------------
__global__ __launch_bounds__(256, 3) void attn_kernel(
    const u16* __restrict__ qb, const u16* __restrict__ kb,
    const u16* __restrict__ vbt, u16* __restrict__ attn)
{
  __shared__ __align__(16) u16 sK[2][64 * 64];  // 16 KB, chunk-swizzled
  __shared__ __align__(16) u16 sV[2][64 * 64];  // 16 KB, chunk-swizzled
  __shared__ __align__(16) u16 sP[4][16][72];   // per-wave P, A-layout
  __shared__ float sAl[4][16];                  // alpha / l transpose slot

  const int tid  = threadIdx.x;
  const int lane = tid & 63;
  const int w    = tid >> 6;

  // descending-length dispatch: qt = 63 first (longest), qt = 0 last
  const int l  = blockIdx.x;          // 0..1023
  const int qt = 63 - (l >> 4);       // 32-row q-tile index
  const int kv = l & 7;
  const int b  = (l >> 3) & 1;
  const int h  = kv * 4 + w;
  const int ktmax = qt >> 1;          // last 64-col k-tile index
  const int moff  = 32 * (qt & 1);    // diag-tile mask offset

  const int lm = lane & 15, lq = lane >> 4;
  const int sw = lm & 7;                          // XOR swizzle key

  // Q fragments (B-operand): qf[nq][c] covers q = qt*32+nq*16+lm, d = c*32+lq*8
  bf16x8 qf[2][2];
  {
    const u16* qhead = qb + ((size_t)(b * NH + h) * T_SEQ + qt * 32) * HD;
    #pragma unroll
    for (int nq = 0; nq < 2; nq++) {
      const u16* qrow = qhead + (size_t)(nq * 16 + lm) * HD + lq * 8;
      qf[nq][0] = *(const bf16x8*)(qrow);
      qf[nq][1] = *(const bf16x8*)(qrow + 32);
    }
  }

  floatx4 o_acc[2][4];
  #pragma unroll
  for (int i = 0; i < 2; i++)
    #pragma unroll
    for (int j = 0; j < 4; j++) { floatx4 z = {0.f,0.f,0.f,0.f}; o_acc[i][j] = z; }
  float m_run[2] = {-1e30f, -1e30f};
  float l_run[2] = {0.f, 0.f};

  const u16* kbase = kb  + (size_t)(b * NKV + kv) * T_SEQ * HD;
  const u16* vbase = vbt + (size_t)(b * NKV + kv) * HD * T_SEQ;

  // precomputed staging lane addresses
  const int p0row = tid >> 3,        p1row = (256 + tid) >> 3;
  const int p0ck  = (tid & 7) ^ (p0row & 7), p1ck = ((256 + tid) & 7) ^ (p1row & 7);
  const u16* kp0 = kbase + (size_t)p0row * HD + p0ck * 8;
  const u16* kp1 = kbase + (size_t)p1row * HD + p1ck * 8;
  const u16* vp0 = vbase + (size_t)p0row * T_SEQ + p0ck * 8;
  const u16* vp1 = vbase + (size_t)p1row * T_SEQ + p1ck * 8;
  const int d0 = tid * 16, d1 = (256 + tid) * 16;

  // per-tile compute body (split-phase)
  auto compute_tile = [&](const u16* sKc, const u16* sVc, const bool diag) {
    bf16x8 kf[4][2], vf[4][2];
    #pragma unroll
    for (int nt = 0; nt < 4; nt++) {
      kf[nt][0] = *(const bf16x8*)(sKc + (((nt*16 + lm) * 8 + (lq ^ sw)) << 3));
      kf[nt][1] = *(const bf16x8*)(sKc + (((nt*16 + lm) * 8 + ((4 + lq) ^ sw)) << 3));
      vf[nt][0] = *(const bf16x8*)(sVc + (((nt*16 + lm) * 8 + (lq ^ sw)) << 3));
      vf[nt][1] = *(const bf16x8*)(sVc + (((nt*16 + lm) * 8 + ((4 + lq) ^ sw)) << 3));
    }

    // ---- Phase 1: S^T for BOTH nq (16 MFMA back-to-back) ----
    floatx4 s_acc[2][4];
    __builtin_amdgcn_s_setprio(1);
    #pragma unroll
    for (int nq = 0; nq < 2; nq++)
      #pragma unroll
      for (int nt = 0; nt < 4; nt++) {
        floatx4 z = {0.f,0.f,0.f,0.f};
        z = __builtin_amdgcn_mfma_f32_16x16x32_bf16(kf[nt][0], qf[nq][0], z, 0, 0, 0);
        z = __builtin_amdgcn_mfma_f32_16x16x32_bf16(kf[nt][1], qf[nq][1], z, 0, 0, 0);
        s_acc[nq][nt] = z;
      }
    __builtin_amdgcn_s_setprio(0);

    // ---- Phase 2: per-nq mask + softmax + PV ----
    #pragma unroll
    for (int nq = 0; nq < 2; nq++) {
      if (diag) {   // diagonal tile: causal mask (k > q)
        #pragma unroll
        for (int nt = 0; nt < 4; nt++)
          #pragma unroll
          for (int r = 0; r < 4; r++)
            if (nt * 16 + lq * 4 + r > nq * 16 + lm + moff) s_acc[nq][nt][r] = -1e30f;
      }

      float mloc = s_acc[nq][0][0];
      #pragma unroll
      for (int nt = 0; nt < 4; nt++)
        #pragma unroll
        for (int r = 0; r < 4; r++) mloc = fmaxf(mloc, s_acc[nq][nt][r]);
      mloc = fmaxf(mloc, __shfl_xor(mloc, 16));
      mloc = fmaxf(mloc, __shfl_xor(mloc, 32));

      // defer-max: only rescale when the tile max outgrows m_run by >8
      float mnew = m_run[nq];
      if (!__all(mloc - m_run[nq] <= 8.0f)) {
        mnew = fmaxf(m_run[nq], mloc);
        float al = fexp2(m_run[nq] - mnew);
        m_run[nq] = mnew;
        l_run[nq] *= al;
        if (lq == 0) sAl[w][lm] = al;
        floatx4 alv = *(const floatx4*)&sAl[w][lq * 4];
        #pragma unroll
        for (int nd = 0; nd < 4; nd++)
          #pragma unroll
          for (int r = 0; r < 4; r++)
            o_acc[nq][nd][r] *= alv[r];
      }

      float rs = 0.f;
      uint2 pk[4];
      #pragma unroll
      for (int nt = 0; nt < 4; nt++) {
        float p0 = fexp2(s_acc[nq][nt][0] - mnew);
        float p1 = fexp2(s_acc[nq][nt][1] - mnew);
        float p2 = fexp2(s_acc[nq][nt][2] - mnew);
        float p3 = fexp2(s_acc[nq][nt][3] - mnew);
        rs += (p0 + p1) + (p2 + p3);
        pk[nt].x = pk2bf(p1, p0);
        pk[nt].y = pk2bf(p3, p2);
      }
      rs += __shfl_xor(rs, 16);
      rs += __shfl_xor(rs, 32);
      l_run[nq] += rs;

      #pragma unroll
      for (int nt = 0; nt < 4; nt++)
        *(uint2*)&sP[w][lm][nt * 16 + lq * 4] = pk[nt];

      __builtin_amdgcn_s_setprio(1);
      #pragma unroll
      for (int st = 0; st < 2; st++) {
        bf16x8 pf = *(const bf16x8*)(&sP[w][lm][st * 32 + lq * 8]);
        #pragma unroll
        for (int nd = 0; nd < 4; nd++)
          o_acc[nq][nd] = __builtin_amdgcn_mfma_f32_16x16x32_bf16(
              pf, vf[nd][st], o_acc[nq][nd], 0, 0, 0);
      }
      __builtin_amdgcn_s_setprio(0);
    }
  };

  const int nst = (ktmax >> 1) + 1;   // stages of two 64-col tiles
  for (int s2 = 0; s2 < nst; s2++) {
    const int kt0  = s2 * 2;
    const int kt1  = kt0 + 1;
    const int kt1c = kt1 < 32 ? kt1 : 31;   // clamp staging addr (valid mem)
    __syncthreads();   // prior stage's sK/sV reads complete
    gld_lds16(kp0 + (size_t)kt0  * 64 * HD, (char*)sK[0] + d0);
    gld_lds16(kp1 + (size_t)kt0  * 64 * HD, (char*)sK[0] + d1);
    gld_lds16(kp0 + (size_t)kt1c * 64 * HD, (char*)sK[1] + d0);
    gld_lds16(kp1 + (size_t)kt1c * 64 * HD, (char*)sK[1] + d1);
    gld_lds16(vp0 + kt0  * 64, (char*)sV[0] + d0);
    gld_lds16(vp1 + kt0  * 64, (char*)sV[0] + d1);
    gld_lds16(vp0 + kt1c * 64, (char*)sV[1] + d0);
    gld_lds16(vp1 + kt1c * 64, (char*)sV[1] + d1);
    __syncthreads();   // staging visible (auto vmcnt(0) drain before barrier)

    compute_tile(sK[0], sV[0], kt0 == ktmax);
    if (kt1 <= ktmax) compute_tile(sK[1], sV[1], kt1 == ktmax);
  }

  // ---- epilogue: per nq transpose l, normalize, store ----
  #pragma unroll
  for (int nq = 0; nq < 2; nq++) {
    __builtin_amdgcn_s_waitcnt(0);  // ensure prior sAl use complete (same wave)
    if (lq == 0) sAl[w][lm] = l_run[nq];
    floatx4 lv = *(const floatx4*)&sAl[w][lq * 4];
    #pragma unroll
    for (int nd = 0; nd < 4; nd++)
      #pragma unroll
      for (int r = 0; r < 4; r++) {
        float v = o_acc[nq][nd][r] / lv[r];
        size_t row = (size_t)b * T_SEQ + qt * 32 + nq * 16 + lq * 4 + r;
        attn[row * DM + h * HD + nd * 16 + lm] = f2bf(v);
      }
  }
}

// ---------------------------------------------------------------------------
extern "C" void kernel_launch(void* const* d_in, const int* in_sizes, int n_in,
                              void* d_out, int out_size, void* d_ws, size_t ws_size,
                              hipStream_t stream)
{
  const float* x    = (const float*)d_in[0];
  const float* cosf = (const float*)d_in[1];
  const float* sinf = (const float*)d_in[2];
  const float* Wq   = (const float*)d_in[3];
  const float* Wk   = (const float*)d_in[4];
  const float* Wv   = (const float*)d_in[5];
  const float* Wo   = (const float*)d_in[6];
  float* out = (float*)d_out;

  char* ws = (char*)d_ws;
  u16* qkvb  = (u16*)(ws + 0);          // 4096x3072 bf16 = 25,165,824
  u16* attnb = (u16*)(ws + 0);          // reuse after prep
  u16* qb    = (u16*)(ws + 25165824);   // 16,777,216
  u16* kb    = (u16*)(ws + 41943040);   //  4,194,304
  u16* vbt   = (u16*)(ws + 46137344);   //  4,194,304
  u16* xb    = (u16*)(ws + 50331648);   // 16,777,216 (dead after gemm_qkv)
  u16* wob   = (u16*)(ws + 50331648);   //  8,388,608 (overwrites xb)
  u16* wqkvb = (u16*)(ws + 67108864);   // 12,582,912

  dim3 blk(256);
  conv_kernel<<<dim3(2048), blk, 0, stream>>>(x, xb, 8388608 / 4);
  conv_wqkv_kernel<<<dim3(1536), blk, 0, stream>>>(Wq, Wk, Wv, wqkvb);

  gemm_qkv_kernel<<<dim3(24, 32), blk, 0, stream>>>(xb, wqkvb, qkvb);

  conv_kernel<<<dim3(1024), blk, 0, stream>>>(Wo, wob, 4194304 / 4);  // wob aliases xb: AFTER gemm_qkv

  prep_kernel<<<dim3(4608), blk, 0, stream>>>(qkvb, cosf, sinf, qb, kb, vbt);
  attn_kernel<<<dim3(1024), blk, 0, stream>>>(qb, kb, vbt, attnb);
  gemm_out_kernel<<<dim3(16, 32), blk, 0, stream>>>(attnb, wob, out);
}

// Round 15
// 279.612 us; speedup vs baseline: 1.0762x; 1.0762x over previous
//
#include <hip/hip_runtime.h>
#include <stdint.h>

// Problem constants
#define B_SZ 2
#define T_SEQ 2048
#define DM 2048
#define NH 32
#define NKV 8
#define HD 64
#define QKV_W 3072

typedef unsigned short u16;
typedef __bf16 bf16x8 __attribute__((ext_vector_type(8)));
typedef float floatx4 __attribute__((ext_vector_type(4)));

__device__ __forceinline__ float bf2f(u16 u) {
  union { unsigned u; float f; } v; v.u = ((unsigned)u) << 16; return v.f;
}
__device__ __forceinline__ u16 f2bf(float f) {
  union { float f; unsigned u; } v; v.f = f;
  unsigned r = v.u + 0x7fff + ((v.u >> 16) & 1);   // RNE
  return (u16)(r >> 16);
}
// pack 2 f32 -> 2 bf16 (truncation) in one v_perm
__device__ __forceinline__ unsigned pk2bf(float hi, float lo) {
  return __builtin_amdgcn_perm(__float_as_uint(hi), __float_as_uint(lo), 0x07060302u);
}
__device__ __forceinline__ float fexp2(float x) {
#if __has_builtin(__builtin_amdgcn_exp2f)
  return __builtin_amdgcn_exp2f(x);
#else
  return exp2f(x);
#endif
}

__device__ __forceinline__ void gld_lds16(const void* g, void* l) {
  __builtin_amdgcn_global_load_lds(
      (const __attribute__((address_space(1))) unsigned int*)g,
      (__attribute__((address_space(3))) unsigned int*)l, 16, 0, 0);
}

// ---------------------------------------------------------------------------
// f32 -> bf16 conversion (RNE), vectorized float4 -> ushort4, grid-stride.
// ---------------------------------------------------------------------------
__global__ __launch_bounds__(256) void conv_kernel(
    const float* __restrict__ src, u16* __restrict__ dst, int n4)
{
  int i = blockIdx.x * 256 + threadIdx.x;
  int stride = gridDim.x * 256;
  for (; i < n4; i += stride) {
    float4 v = ((const float4*)src)[i];
    ushort4 o;
    o.x = f2bf(v.x); o.y = f2bf(v.y); o.z = f2bf(v.z); o.w = f2bf(v.w);
    ((ushort4*)dst)[i] = o;
  }
}

// ---------------------------------------------------------------------------
// Fused Wq/Wk/Wv f32->bf16 conversion. dst regions in wqkvb are contiguous.
// (Round-10's further merge with the x conv regressed ~6us — keep split.)
// ---------------------------------------------------------------------------
__global__ __launch_bounds__(256) void conv_wqkv_kernel(
    const float* __restrict__ Wq, const float* __restrict__ Wk,
    const float* __restrict__ Wv, u16* __restrict__ dst)
{
  int i = blockIdx.x * 256 + threadIdx.x;
  int stride = gridDim.x * 256;
  for (; i < 1572864; i += stride) {
    float4 v;
    if (i < 1048576)      v = ((const float4*)Wq)[i];
    else if (i < 1310720) v = ((const float4*)Wk)[i - 1048576];
    else                  v = ((const float4*)Wv)[i - 1310720];
    ushort4 o;
    o.x = f2bf(v.x); o.y = f2bf(v.y); o.z = f2bf(v.z); o.w = f2bf(v.w);
    ((ushort4*)dst)[i] = o;
  }
}

// ---------------------------------------------------------------------------
// GEMM1: qkv[4096,3072](bf16) = xb[4096,2048](bf16) @ wqkvb[3072,2048]^T
// Single-buffer two-barrier K-loop, BK=64, chunk-XOR swizzled LDS (0 bank
// conflicts, verified r9) — the PROVEN ~58us config (rounds 8-12).
// GEMM pipelining RETIRED after 3 failures: r5 cur-indexed dbuf (+8us,
// VALU addr overhead), r13/14 static-unroll dbuf (LDS 64KB -> occupancy
// 15.5%, +21us — m132 cliff). Round-9: no fused epilogues (VGPR 68->116).
// NEW (r15): XCD-chunked block swizzle (T1) — linear id L runs on XCD L%8;
// remap wid=(L%8)*96+L/8 so each XCD owns 4 contiguous m-rows x all n:
// A-panels (2MB) stay resident in that XCD's 4MB L2. FETCH 71.7MB -> ~40MB.
// 768 % 8 == 0 -> bijective.
// ---------------------------------------------------------------------------
__global__ __launch_bounds__(256) void gemm_qkv_kernel(
    const u16* __restrict__ A, const u16* __restrict__ Bt,
    u16* __restrict__ C)
{
  __shared__ __align__(16) u16 sA[128 * 64];   // 16 KB
  __shared__ __align__(16) u16 sB[128 * 64];   // 16 KB

  // XCD-chunked swizzle (grid 24x32 = 768 blocks, 96 per XCD chunk)
  const int L   = blockIdx.y * 24 + blockIdx.x;
  const int wid = (L % 8) * 96 + (L / 8);
  const int n0 = (wid % 24) * 128;
  const int m0 = (wid / 24) * 128;
  const int K = 2048;

  const int tid  = threadIdx.x;
  const int lane = tid & 63;
  const int w    = tid >> 6;
  const int wm = w >> 1, wn = w & 1;
  const int lm = lane & 15, lq = lane >> 4;

  floatx4 acc[4][4];
  #pragma unroll
  for (int i = 0; i < 4; i++)
    #pragma unroll
    for (int j = 0; j < 4; j++) { floatx4 z = {0.f,0.f,0.f,0.f}; acc[i][j] = z; }

  // staging: pass p covers rows p*32 + (tid>>3); chunk = (tid&7)^((tid>>3)&7)
  const int srow   = tid >> 3;
  const int schunk = (tid & 7) ^ (srow & 7);
  const u16* ApG = A  + (size_t)(m0 + srow) * K + schunk * 8;
  const u16* BpG = Bt + (size_t)(n0 + srow) * K + schunk * 8;
  u16* sAd = sA + tid * 8;
  u16* sBd = sB + tid * 8;

  // fragment read bases; slot (kk*4+lq)^sw holds global chunk kk*4+lq
  const int sw  = lm & 7;
  const int rba = (wm * 64 + lm) * 64;
  const int rbb = (wn * 64 + lm) * 64;
  const int c0  = (lq ^ sw) * 8;
  const int c1  = ((4 + lq) ^ sw) * 8;

  for (int k0 = 0; k0 < K; k0 += 64) {
    #pragma unroll
    for (int p = 0; p < 4; p++) {
      gld_lds16(ApG + (size_t)p * 32 * K + k0, sAd + p * 2048);
      gld_lds16(BpG + (size_t)p * 32 * K + k0, sBd + p * 2048);
    }
    __syncthreads();   // drain staging (auto vmcnt(0)); tile visible

    #pragma unroll
    for (int kk = 0; kk < 2; kk++) {
      const int ck = kk ? c1 : c0;
      bf16x8 af[4], bfr[4];
      #pragma unroll
      for (int mi = 0; mi < 4; mi++)
        af[mi] = *(const bf16x8*)(sA + rba + mi * 1024 + ck);
      #pragma unroll
      for (int ni = 0; ni < 4; ni++)
        bfr[ni] = *(const bf16x8*)(sB + rbb + ni * 1024 + ck);

      #pragma unroll
      for (int mi = 0; mi < 4; mi++)
        #pragma unroll
        for (int ni = 0; ni < 4; ni++)
          acc[mi][ni] = __builtin_amdgcn_mfma_f32_16x16x32_bf16(
              af[mi], bfr[ni], acc[mi][ni], 0, 0, 0);
    }
    __syncthreads();   // all reads done before restaging
  }

  #pragma unroll
  for (int mi = 0; mi < 4; mi++)
    #pragma unroll
    for (int ni = 0; ni < 4; ni++)
      #pragma unroll
      for (int r = 0; r < 4; r++) {
        int row = m0 + wm*64 + mi*16 + lq*4 + r;
        int col = n0 + wn*64 + ni*16 + lm;
        C[(size_t)row * QKV_W + col] = f2bf(acc[mi][ni][r]);
      }
}

// ---------------------------------------------------------------------------
// GEMM2: out[4096,2048](f32) = attn[4096,2048](bf16) @ wob[2048,2048]^T(bf16)
// Same single-buffer BK=64 structure; XCD swizzle (512 blocks, 64/chunk).
// ---------------------------------------------------------------------------
__global__ __launch_bounds__(256) void gemm_out_kernel(
    const u16* __restrict__ A, const u16* __restrict__ Bt,
    float* __restrict__ C)
{
  __shared__ __align__(16) u16 sA[128 * 64];
  __shared__ __align__(16) u16 sB[128 * 64];

  // XCD-chunked swizzle (grid 16x32 = 512 blocks, 64 per XCD chunk)
  const int L   = blockIdx.y * 16 + blockIdx.x;
  const int wid = (L % 8) * 64 + (L / 8);
  const int n0 = (wid % 16) * 128;
  const int m0 = (wid / 16) * 128;
  const int K = 2048;

  const int tid  = threadIdx.x;
  const int lane = tid & 63;
  const int w    = tid >> 6;
  const int wm = w >> 1, wn = w & 1;
  const int lm = lane & 15, lq = lane >> 4;

  floatx4 acc[4][4];
  #pragma unroll
  for (int i = 0; i < 4; i++)
    #pragma unroll
    for (int j = 0; j < 4; j++) { floatx4 z = {0.f,0.f,0.f,0.f}; acc[i][j] = z; }

  const int srow   = tid >> 3;
  const int schunk = (tid & 7) ^ (srow & 7);
  const u16* ApG = A  + (size_t)(m0 + srow) * K + schunk * 8;
  const u16* BpG = Bt + (size_t)(n0 + srow) * K + schunk * 8;
  u16* sAd = sA + tid * 8;
  u16* sBd = sB + tid * 8;

  const int sw  = lm & 7;
  const int rba = (wm * 64 + lm) * 64;
  const int rbb = (wn * 64 + lm) * 64;
  const int c0  = (lq ^ sw) * 8;
  const int c1  = ((4 + lq) ^ sw) * 8;

  for (int k0 = 0; k0 < K; k0 += 64) {
    #pragma unroll
    for (int p = 0; p < 4; p++) {
      gld_lds16(ApG + (size_t)p * 32 * K + k0, sAd + p * 2048);
      gld_lds16(BpG + (size_t)p * 32 * K + k0, sBd + p * 2048);
    }
    __syncthreads();

    #pragma unroll
    for (int kk = 0; kk < 2; kk++) {
      const int ck = kk ? c1 : c0;
      bf16x8 af[4], bfr[4];
      #pragma unroll
      for (int mi = 0; mi < 4; mi++)
        af[mi] = *(const bf16x8*)(sA + rba + mi * 1024 + ck);
      #pragma unroll
      for (int ni = 0; ni < 4; ni++)
        bfr[ni] = *(const bf16x8*)(sB + rbb + ni * 1024 + ck);

      #pragma unroll
      for (int mi = 0; mi < 4; mi++)
        #pragma unroll
        for (int ni = 0; ni < 4; ni++)
          acc[mi][ni] = __builtin_amdgcn_mfma_f32_16x16x32_bf16(
              af[mi], bfr[ni], acc[mi][ni], 0, 0, 0);
    }
    __syncthreads();
  }

  #pragma unroll
  for (int mi = 0; mi < 4; mi++)
    #pragma unroll
    for (int ni = 0; ni < 4; ni++)
      #pragma unroll
      for (int r = 0; r < 4; r++) {
        int row = m0 + wm*64 + mi*16 + lq*4 + r;
        int col = n0 + wn*64 + ni*16 + lm;
        C[(size_t)row * DM + col] = acc[mi][ni][r];
      }
}

// ---------------------------------------------------------------------------
// Merged prep: RoPE (blocks 0..4095) + V transpose (blocks 4096..4607).
// Block-level concatenation — bodies byte-identical to the proven standalone
// kernels (round-10 lesson: don't interleave streams within a loop).
// ---------------------------------------------------------------------------
#define QSCALE 0.180336880f   // 0.125 * 1.44269504
__global__ __launch_bounds__(256) void prep_kernel(
    const u16* __restrict__ qkv, const float* __restrict__ cosf,
    const float* __restrict__ sinf, u16* __restrict__ qb,
    u16* __restrict__ kb, u16* __restrict__ vbt)
{
  __shared__ u16 tile[64][66];     // used by vtrans branch only
  const int tid = threadIdx.x;

  if (blockIdx.x < 4096) {
    // ---- RoPE ----
    const int bt = blockIdx.x;
    const int b = bt / T_SEQ, t = bt % T_SEQ;
    const u16* row = qkv + (size_t)bt * QKV_W;

    #pragma unroll
    for (int i = 0; i < 4; i++) {
      int idx = i * 256 + tid;          // 0..1023
      int h = idx >> 5, dp = idx & 31;
      float x1 = bf2f(row[h * 64 + dp]);
      float x2 = bf2f(row[h * 64 + dp + 32]);
      float c = cosf[t * 64 + dp];
      float s = sinf[t * 64 + dp];
      float o1 = (x1 * c - x2 * s) * QSCALE;
      float o2 = (x2 * c + x1 * s) * QSCALE;
      size_t base = ((size_t)(b * NH + h) * T_SEQ + t) * HD + dp;
      qb[base]      = f2bf(o1);
      qb[base + 32] = f2bf(o2);
    }
    {
      int idx = tid;                    // 0..255
      int kvh = idx >> 5, dp = idx & 31;
      float x1 = bf2f(row[2048 + kvh * 64 + dp]);
      float x2 = bf2f(row[2048 + kvh * 64 + dp + 32]);
      float c = cosf[t * 64 + dp];
      float s = sinf[t * 64 + dp];
      size_t base = ((size_t)(b * NKV + kvh) * T_SEQ + t) * HD + dp;
      kb[base]      = f2bf(x1 * c - x2 * s);
      kb[base + 32] = f2bf(x2 * c + x1 * s);
    }
  } else {
    // ---- V transpose: qkv cols [2560,3072) -> vbt (B,KV,64,T) ----
    const int idx2 = blockIdx.x - 4096;   // 0..511
    const int t0  = (idx2 & 31) * 64;
    const int kvh = (idx2 >> 5) & 7;
    const int b   = idx2 >> 8;

    #pragma unroll
    for (int i = 0; i < 16; i++) {
      int idx = i * 256 + tid;
      int r = idx >> 6, c = idx & 63;
      tile[r][c] = qkv[(size_t)(b * T_SEQ + t0 + r) * QKV_W + 2560 + kvh * 64 + c];
    }
    __syncthreads();
    #pragma unroll
    for (int i = 0; i < 16; i++) {
      int idx = i * 256 + tid;
      int d = idx >> 6, c = idx & 63;
      vbt[((size_t)(b * NKV + kvh) * HD + d) * T_SEQ + t0 + c] = tile[c][d];
    }
  }
}

// ---------------------------------------------------------------------------
// Flash attention v9 (GQA-fused, 32-row q-tiles, paired-tile staging,
// split-phase tile body — round-12, perf-neutral vs v8 but kept).
// Two-barrier sync template (deterministic; single-barrier dbuf retired r6).
// launch_bounds(256,3); defer-max (THR=8, log2); setprio around MFMA;
// 1024-block descending LPT grid. LDS ~42 KB -> 3 blocks/CU.
// ---------------------------------------------------------------------------
__global__ __launch_bounds__(256, 3) void attn_kernel(
    const u16* __restrict__ qb, const u16* __restrict__ kb,
    const u16* __restrict__ vbt, u16* __restrict__ attn)
{
  __shared__ __align__(16) u16 sK[2][64 * 64];  // 16 KB, chunk-swizzled
  __shared__ __align__(16) u16 sV[2][64 * 64];  // 16 KB, chunk-swizzled
  __shared__ __align__(16) u16 sP[4][16][72];   // per-wave P, A-layout
  __shared__ float sAl[4][16];                  // alpha / l transpose slot

  const int tid  = threadIdx.x;
  const int lane = tid & 63;
  const int w    = tid >> 6;

  // descending-length dispatch: qt = 63 first (longest), qt = 0 last
  const int l  = blockIdx.x;          // 0..1023
  const int qt = 63 - (l >> 4);       // 32-row q-tile index
  const int kv = l & 7;
  const int b  = (l >> 3) & 1;
  const int h  = kv * 4 + w;
  const int ktmax = qt >> 1;          // last 64-col k-tile index
  const int moff  = 32 * (qt & 1);    // diag-tile mask offset

  const int lm = lane & 15, lq = lane >> 4;
  const int sw = lm & 7;                          // XOR swizzle key

  // Q fragments (B-operand): qf[nq][c] covers q = qt*32+nq*16+lm, d = c*32+lq*8
  bf16x8 qf[2][2];
  {
    const u16* qhead = qb + ((size_t)(b * NH + h) * T_SEQ + qt * 32) * HD;
    #pragma unroll
    for (int nq = 0; nq < 2; nq++) {
      const u16* qrow = qhead + (size_t)(nq * 16 + lm) * HD + lq * 8;
      qf[nq][0] = *(const bf16x8*)(qrow);
      qf[nq][1] = *(const bf16x8*)(qrow + 32);
    }
  }

  floatx4 o_acc[2][4];
  #pragma unroll
  for (int i = 0; i < 2; i++)
    #pragma unroll
    for (int j = 0; j < 4; j++) { floatx4 z = {0.f,0.f,0.f,0.f}; o_acc[i][j] = z; }
  float m_run[2] = {-1e30f, -1e30f};
  float l_run[2] = {0.f, 0.f};

  const u16* kbase = kb  + (size_t)(b * NKV + kv) * T_SEQ * HD;
  const u16* vbase = vbt + (size_t)(b * NKV + kv) * HD * T_SEQ;

  // precomputed staging lane addresses
  const int p0row = tid >> 3,        p1row = (256 + tid) >> 3;
  const int p0ck  = (tid & 7) ^ (p0row & 7), p1ck = ((256 + tid) & 7) ^ (p1row & 7);
  const u16* kp0 = kbase + (size_t)p0row * HD + p0ck * 8;
  const u16* kp1 = kbase + (size_t)p1row * HD + p1ck * 8;
  const u16* vp0 = vbase + (size_t)p0row * T_SEQ + p0ck * 8;
  const u16* vp1 = vbase + (size_t)p1row * T_SEQ + p1ck * 8;
  const int d0 = tid * 16, d1 = (256 + tid) * 16;

  // per-tile compute body (split-phase)
  auto compute_tile = [&](const u16* sKc, const u16* sVc, const bool diag) {
    bf16x8 kf[4][2], vf[4][2];
    #pragma unroll
    for (int nt = 0; nt < 4; nt++) {
      kf[nt][0] = *(const bf16x8*)(sKc + (((nt*16 + lm) * 8 + (lq ^ sw)) << 3));
      kf[nt][1] = *(const bf16x8*)(sKc + (((nt*16 + lm) * 8 + ((4 + lq) ^ sw)) << 3));
      vf[nt][0] = *(const bf16x8*)(sVc + (((nt*16 + lm) * 8 + (lq ^ sw)) << 3));
      vf[nt][1] = *(const bf16x8*)(sVc + (((nt*16 + lm) * 8 + ((4 + lq) ^ sw)) << 3));
    }

    // ---- Phase 1: S^T for BOTH nq (16 MFMA back-to-back) ----
    floatx4 s_acc[2][4];
    __builtin_amdgcn_s_setprio(1);
    #pragma unroll
    for (int nq = 0; nq < 2; nq++)
      #pragma unroll
      for (int nt = 0; nt < 4; nt++) {
        floatx4 z = {0.f,0.f,0.f,0.f};
        z = __builtin_amdgcn_mfma_f32_16x16x32_bf16(kf[nt][0], qf[nq][0], z, 0, 0, 0);
        z = __builtin_amdgcn_mfma_f32_16x16x32_bf16(kf[nt][1], qf[nq][1], z, 0, 0, 0);
        s_acc[nq][nt] = z;
      }
    __builtin_amdgcn_s_setprio(0);

    // ---- Phase 2: per-nq mask + softmax + PV ----
    #pragma unroll
    for (int nq = 0; nq < 2; nq++) {
      if (diag) {   // diagonal tile: causal mask (k > q)
        #pragma unroll
        for (int nt = 0; nt < 4; nt++)
          #pragma unroll
          for (int r = 0; r < 4; r++)
            if (nt * 16 + lq * 4 + r > nq * 16 + lm + moff) s_acc[nq][nt][r] = -1e30f;
      }

      float mloc = s_acc[nq][0][0];
      #pragma unroll
      for (int nt = 0; nt < 4; nt++)
        #pragma unroll
        for (int r = 0; r < 4; r++) mloc = fmaxf(mloc, s_acc[nq][nt][r]);
      mloc = fmaxf(mloc, __shfl_xor(mloc, 16));
      mloc = fmaxf(mloc, __shfl_xor(mloc, 32));

      // defer-max: only rescale when the tile max outgrows m_run by >8
      float mnew = m_run[nq];
      if (!__all(mloc - m_run[nq] <= 8.0f)) {
        mnew = fmaxf(m_run[nq], mloc);
        float al = fexp2(m_run[nq] - mnew);
        m_run[nq] = mnew;
        l_run[nq] *= al;
        if (lq == 0) sAl[w][lm] = al;
        floatx4 alv = *(const floatx4*)&sAl[w][lq * 4];
        #pragma unroll
        for (int nd = 0; nd < 4; nd++)
          #pragma unroll
          for (int r = 0; r < 4; r++)
            o_acc[nq][nd][r] *= alv[r];
      }

      float rs = 0.f;
      uint2 pk[4];
      #pragma unroll
      for (int nt = 0; nt < 4; nt++) {
        float p0 = fexp2(s_acc[nq][nt][0] - mnew);
        float p1 = fexp2(s_acc[nq][nt][1] - mnew);
        float p2 = fexp2(s_acc[nq][nt][2] - mnew);
        float p3 = fexp2(s_acc[nq][nt][3] - mnew);
        rs += (p0 + p1) + (p2 + p3);
        pk[nt].x = pk2bf(p1, p0);
        pk[nt].y = pk2bf(p3, p2);
      }
      rs += __shfl_xor(rs, 16);
      rs += __shfl_xor(rs, 32);
      l_run[nq] += rs;

      #pragma unroll
      for (int nt = 0; nt < 4; nt++)
        *(uint2*)&sP[w][lm][nt * 16 + lq * 4] = pk[nt];

      __builtin_amdgcn_s_setprio(1);
      #pragma unroll
      for (int st = 0; st < 2; st++) {
        bf16x8 pf = *(const bf16x8*)(&sP[w][lm][st * 32 + lq * 8]);
        #pragma unroll
        for (int nd = 0; nd < 4; nd++)
          o_acc[nq][nd] = __builtin_amdgcn_mfma_f32_16x16x32_bf16(
              pf, vf[nd][st], o_acc[nq][nd], 0, 0, 0);
      }
      __builtin_amdgcn_s_setprio(0);
    }
  };

  const int nst = (ktmax >> 1) + 1;   // stages of two 64-col tiles
  for (int s2 = 0; s2 < nst; s2++) {
    const int kt0  = s2 * 2;
    const int kt1  = kt0 + 1;
    const int kt1c = kt1 < 32 ? kt1 : 31;   // clamp staging addr (valid mem)
    __syncthreads();   // prior stage's sK/sV reads complete
    gld_lds16(kp0 + (size_t)kt0  * 64 * HD, (char*)sK[0] + d0);
    gld_lds16(kp1 + (size_t)kt0  * 64 * HD, (char*)sK[0] + d1);
    gld_lds16(kp0 + (size_t)kt1c * 64 * HD, (char*)sK[1] + d0);
    gld_lds16(kp1 + (size_t)kt1c * 64 * HD, (char*)sK[1] + d1);
    gld_lds16(vp0 + kt0  * 64, (char*)sV[0] + d0);
    gld_lds16(vp1 + kt0  * 64, (char*)sV[0] + d1);
    gld_lds16(vp0 + kt1c * 64, (char*)sV[1] + d0);
    gld_lds16(vp1 + kt1c * 64, (char*)sV[1] + d1);
    __syncthreads();   // staging visible (auto vmcnt(0) drain before barrier)

    compute_tile(sK[0], sV[0], kt0 == ktmax);
    if (kt1 <= ktmax) compute_tile(sK[1], sV[1], kt1 == ktmax);
  }

  // ---- epilogue: per nq transpose l, normalize, store ----
  #pragma unroll
  for (int nq = 0; nq < 2; nq++) {
    __builtin_amdgcn_s_waitcnt(0);  // ensure prior sAl use complete (same wave)
    if (lq == 0) sAl[w][lm] = l_run[nq];
    floatx4 lv = *(const floatx4*)&sAl[w][lq * 4];
    #pragma unroll
    for (int nd = 0; nd < 4; nd++)
      #pragma unroll
      for (int r = 0; r < 4; r++) {
        float v = o_acc[nq][nd][r] / lv[r];
        size_t row = (size_t)b * T_SEQ + qt * 32 + nq * 16 + lq * 4 + r;
        attn[row * DM + h * HD + nd * 16 + lm] = f2bf(v);
      }
  }
}

// ---------------------------------------------------------------------------
extern "C" void kernel_launch(void* const* d_in, const int* in_sizes, int n_in,
                              void* d_out, int out_size, void* d_ws, size_t ws_size,
                              hipStream_t stream)
{
  const float* x    = (const float*)d_in[0];
  const float* cosf = (const float*)d_in[1];
  const float* sinf = (const float*)d_in[2];
  const float* Wq   = (const float*)d_in[3];
  const float* Wk   = (const float*)d_in[4];
  const float* Wv   = (const float*)d_in[5];
  const float* Wo   = (const float*)d_in[6];
  float* out = (float*)d_out;

  char* ws = (char*)d_ws;
  u16* qkvb  = (u16*)(ws + 0);          // 4096x3072 bf16 = 25,165,824
  u16* attnb = (u16*)(ws + 0);          // reuse after prep
  u16* qb    = (u16*)(ws + 25165824);   // 16,777,216
  u16* kb    = (u16*)(ws + 41943040);   //  4,194,304
  u16* vbt   = (u16*)(ws + 46137344);   //  4,194,304
  u16* xb    = (u16*)(ws + 50331648);   // 16,777,216 (dead after gemm_qkv)
  u16* wob   = (u16*)(ws + 50331648);   //  8,388,608 (overwrites xb)
  u16* wqkvb = (u16*)(ws + 67108864);   // 12,582,912

  dim3 blk(256);
  conv_kernel<<<dim3(2048), blk, 0, stream>>>(x, xb, 8388608 / 4);
  conv_wqkv_kernel<<<dim3(1536), blk, 0, stream>>>(Wq, Wk, Wv, wqkvb);

  gemm_qkv_kernel<<<dim3(24, 32), blk, 0, stream>>>(xb, wqkvb, qkvb);

  conv_kernel<<<dim3(1024), blk, 0, stream>>>(Wo, wob, 4194304 / 4);  // wob aliases xb: AFTER gemm_qkv

  prep_kernel<<<dim3(4608), blk, 0, stream>>>(qkvb, cosf, sinf, qb, kb, vbt);
  attn_kernel<<<dim3(1024), blk, 0, stream>>>(qb, kb, vbt, attnb);
  gemm_out_kernel<<<dim3(16, 32), blk, 0, stream>>>(attnb, wob, out);
}

// Round 16
// 275.352 us; speedup vs baseline: 1.0928x; 1.0155x over previous
//
#include <hip/hip_runtime.h>
#include <stdint.h>

// Problem constants
#define B_SZ 2
#define T_SEQ 2048
#define DM 2048
#define NH 32
#define NKV 8
#define HD 64
#define QKV_W 3072

typedef unsigned short u16;
typedef __bf16 bf16x8 __attribute__((ext_vector_type(8)));
typedef float floatx4 __attribute__((ext_vector_type(4)));

__device__ __forceinline__ float bf2f(u16 u) {
  union { unsigned u; float f; } v; v.u = ((unsigned)u) << 16; return v.f;
}
__device__ __forceinline__ u16 f2bf(float f) {
  union { float f; unsigned u; } v; v.f = f;
  unsigned r = v.u + 0x7fff + ((v.u >> 16) & 1);   // RNE
  return (u16)(r >> 16);
}
// pack 2 f32 -> 2 bf16 (truncation) in one v_perm
__device__ __forceinline__ unsigned pk2bf(float hi, float lo) {
  return __builtin_amdgcn_perm(__float_as_uint(hi), __float_as_uint(lo), 0x07060302u);
}
__device__ __forceinline__ float fexp2(float x) {
#if __has_builtin(__builtin_amdgcn_exp2f)
  return __builtin_amdgcn_exp2f(x);
#else
  return exp2f(x);
#endif
}

__device__ __forceinline__ void gld_lds16(const void* g, void* l) {
  __builtin_amdgcn_global_load_lds(
      (const __attribute__((address_space(1))) unsigned int*)g,
      (__attribute__((address_space(3))) unsigned int*)l, 16, 0, 0);
}

__device__ __forceinline__ ushort4 cvt4(float4 v) {
  ushort4 o;
  o.x = f2bf(v.x); o.y = f2bf(v.y); o.z = f2bf(v.z); o.w = f2bf(v.w);
  return o;
}

// ---------------------------------------------------------------------------
// Merged input conversions (block-level concatenation, r11-proven pattern —
// NOT the r10 interleaved-stream merge that regressed):
//   blocks 0..2047    : x  f32->bf16 (2097152 ushort4, stride 2048*256)
//   blocks 2048..3583 : Wq/Wk/Wv -> wqkvb (1572864 ushort4, stride 1536*256)
// Each branch's loop bounds/stride are identical to its former standalone
// kernel, so access patterns are unchanged.
// ---------------------------------------------------------------------------
__global__ __launch_bounds__(256) void conv_in_kernel(
    const float* __restrict__ x,  u16* __restrict__ xb,
    const float* __restrict__ Wq, const float* __restrict__ Wk,
    const float* __restrict__ Wv, u16* __restrict__ wqkvb)
{
  const int tid = threadIdx.x;
  if (blockIdx.x < 2048) {
    int i = blockIdx.x * 256 + tid;
    const int stride = 2048 * 256;
    for (; i < 2097152; i += stride)
      ((ushort4*)xb)[i] = cvt4(((const float4*)x)[i]);
  } else {
    int i = (blockIdx.x - 2048) * 256 + tid;
    const int stride = 1536 * 256;
    for (; i < 1572864; i += stride) {
      float4 v;
      if (i < 1048576)      v = ((const float4*)Wq)[i];
      else if (i < 1310720) v = ((const float4*)Wk)[i - 1048576];
      else                  v = ((const float4*)Wv)[i - 1310720];
      ((ushort4*)wqkvb)[i] = cvt4(v);
    }
  }
}

// ---------------------------------------------------------------------------
// GEMM1: qkv[4096,3072](bf16) = xb[4096,2048](bf16) @ wqkvb[3072,2048]^T
// Single-buffer two-barrier K-loop, BK=64, chunk-XOR swizzled LDS (0 bank
// conflicts, verified r9) — the PROVEN config. XCD-chunked block swizzle
// (T1, r15: total -8.5us): each XCD owns 4 contiguous m-rows x all n, so
// A-panels (2MB) stay L2-resident. 768 % 8 == 0 -> bijective.
// GEMM pipelining RETIRED (r5: +8us VALU addr overhead; r13/14: LDS 64KB
// occupancy cliff +21us). Round-9: no fused epilogues (VGPR 68->116).
// ---------------------------------------------------------------------------
__global__ __launch_bounds__(256) void gemm_qkv_kernel(
    const u16* __restrict__ A, const u16* __restrict__ Bt,
    u16* __restrict__ C)
{
  __shared__ __align__(16) u16 sA[128 * 64];   // 16 KB
  __shared__ __align__(16) u16 sB[128 * 64];   // 16 KB

  // XCD-chunked swizzle (grid 24x32 = 768 blocks, 96 per XCD chunk)
  const int L   = blockIdx.y * 24 + blockIdx.x;
  const int wid = (L % 8) * 96 + (L / 8);
  const int n0 = (wid % 24) * 128;
  const int m0 = (wid / 24) * 128;
  const int K = 2048;

  const int tid  = threadIdx.x;
  const int lane = tid & 63;
  const int w    = tid >> 6;
  const int wm = w >> 1, wn = w & 1;
  const int lm = lane & 15, lq = lane >> 4;

  floatx4 acc[4][4];
  #pragma unroll
  for (int i = 0; i < 4; i++)
    #pragma unroll
    for (int j = 0; j < 4; j++) { floatx4 z = {0.f,0.f,0.f,0.f}; acc[i][j] = z; }

  // staging: pass p covers rows p*32 + (tid>>3); chunk = (tid&7)^((tid>>3)&7)
  const int srow   = tid >> 3;
  const int schunk = (tid & 7) ^ (srow & 7);
  const u16* ApG = A  + (size_t)(m0 + srow) * K + schunk * 8;
  const u16* BpG = Bt + (size_t)(n0 + srow) * K + schunk * 8;
  u16* sAd = sA + tid * 8;
  u16* sBd = sB + tid * 8;

  // fragment read bases; slot (kk*4+lq)^sw holds global chunk kk*4+lq
  const int sw  = lm & 7;
  const int rba = (wm * 64 + lm) * 64;
  const int rbb = (wn * 64 + lm) * 64;
  const int c0  = (lq ^ sw) * 8;
  const int c1  = ((4 + lq) ^ sw) * 8;

  for (int k0 = 0; k0 < K; k0 += 64) {
    #pragma unroll
    for (int p = 0; p < 4; p++) {
      gld_lds16(ApG + (size_t)p * 32 * K + k0, sAd + p * 2048);
      gld_lds16(BpG + (size_t)p * 32 * K + k0, sBd + p * 2048);
    }
    __syncthreads();   // drain staging (auto vmcnt(0)); tile visible

    #pragma unroll
    for (int kk = 0; kk < 2; kk++) {
      const int ck = kk ? c1 : c0;
      bf16x8 af[4], bfr[4];
      #pragma unroll
      for (int mi = 0; mi < 4; mi++)
        af[mi] = *(const bf16x8*)(sA + rba + mi * 1024 + ck);
      #pragma unroll
      for (int ni = 0; ni < 4; ni++)
        bfr[ni] = *(const bf16x8*)(sB + rbb + ni * 1024 + ck);

      #pragma unroll
      for (int mi = 0; mi < 4; mi++)
        #pragma unroll
        for (int ni = 0; ni < 4; ni++)
          acc[mi][ni] = __builtin_amdgcn_mfma_f32_16x16x32_bf16(
              af[mi], bfr[ni], acc[mi][ni], 0, 0, 0);
    }
    __syncthreads();   // all reads done before restaging
  }

  #pragma unroll
  for (int mi = 0; mi < 4; mi++)
    #pragma unroll
    for (int ni = 0; ni < 4; ni++)
      #pragma unroll
      for (int r = 0; r < 4; r++) {
        int row = m0 + wm*64 + mi*16 + lq*4 + r;
        int col = n0 + wn*64 + ni*16 + lm;
        C[(size_t)row * QKV_W + col] = f2bf(acc[mi][ni][r]);
      }
}

// ---------------------------------------------------------------------------
// GEMM2: out[4096,2048](f32) = attn[4096,2048](bf16) @ wob[2048,2048]^T(bf16)
// Same single-buffer BK=64 structure; XCD swizzle (512 blocks, 64/chunk).
// ---------------------------------------------------------------------------
__global__ __launch_bounds__(256) void gemm_out_kernel(
    const u16* __restrict__ A, const u16* __restrict__ Bt,
    float* __restrict__ C)
{
  __shared__ __align__(16) u16 sA[128 * 64];
  __shared__ __align__(16) u16 sB[128 * 64];

  // XCD-chunked swizzle (grid 16x32 = 512 blocks, 64 per XCD chunk)
  const int L   = blockIdx.y * 16 + blockIdx.x;
  const int wid = (L % 8) * 64 + (L / 8);
  const int n0 = (wid % 16) * 128;
  const int m0 = (wid / 16) * 128;
  const int K = 2048;

  const int tid  = threadIdx.x;
  const int lane = tid & 63;
  const int w    = tid >> 6;
  const int wm = w >> 1, wn = w & 1;
  const int lm = lane & 15, lq = lane >> 4;

  floatx4 acc[4][4];
  #pragma unroll
  for (int i = 0; i < 4; i++)
    #pragma unroll
    for (int j = 0; j < 4; j++) { floatx4 z = {0.f,0.f,0.f,0.f}; acc[i][j] = z; }

  const int srow   = tid >> 3;
  const int schunk = (tid & 7) ^ (srow & 7);
  const u16* ApG = A  + (size_t)(m0 + srow) * K + schunk * 8;
  const u16* BpG = Bt + (size_t)(n0 + srow) * K + schunk * 8;
  u16* sAd = sA + tid * 8;
  u16* sBd = sB + tid * 8;

  const int sw  = lm & 7;
  const int rba = (wm * 64 + lm) * 64;
  const int rbb = (wn * 64 + lm) * 64;
  const int c0  = (lq ^ sw) * 8;
  const int c1  = ((4 + lq) ^ sw) * 8;

  for (int k0 = 0; k0 < K; k0 += 64) {
    #pragma unroll
    for (int p = 0; p < 4; p++) {
      gld_lds16(ApG + (size_t)p * 32 * K + k0, sAd + p * 2048);
      gld_lds16(BpG + (size_t)p * 32 * K + k0, sBd + p * 2048);
    }
    __syncthreads();

    #pragma unroll
    for (int kk = 0; kk < 2; kk++) {
      const int ck = kk ? c1 : c0;
      bf16x8 af[4], bfr[4];
      #pragma unroll
      for (int mi = 0; mi < 4; mi++)
        af[mi] = *(const bf16x8*)(sA + rba + mi * 1024 + ck);
      #pragma unroll
      for (int ni = 0; ni < 4; ni++)
        bfr[ni] = *(const bf16x8*)(sB + rbb + ni * 1024 + ck);

      #pragma unroll
      for (int mi = 0; mi < 4; mi++)
        #pragma unroll
        for (int ni = 0; ni < 4; ni++)
          acc[mi][ni] = __builtin_amdgcn_mfma_f32_16x16x32_bf16(
              af[mi], bfr[ni], acc[mi][ni], 0, 0, 0);
    }
    __syncthreads();
  }

  #pragma unroll
  for (int mi = 0; mi < 4; mi++)
    #pragma unroll
    for (int ni = 0; ni < 4; ni++)
      #pragma unroll
      for (int r = 0; r < 4; r++) {
        int row = m0 + wm*64 + mi*16 + lq*4 + r;
        int col = n0 + wn*64 + ni*16 + lm;
        C[(size_t)row * DM + col] = acc[mi][ni][r];
      }
}

// ---------------------------------------------------------------------------
// Merged prep (runs after gemm_qkv; block-level concatenation):
//   blocks 0..1023    : Wo f32->bf16 -> wob (wob aliases xb, dead by now)
//   blocks 1024..5119 : RoPE (qkv -> qb, kb)
//   blocks 5120..5631 : V transpose (qkv cols [2560,3072) -> vbt)
// Bodies byte-identical to the proven standalone kernels.
// ---------------------------------------------------------------------------
#define QSCALE 0.180336880f   // 0.125 * 1.44269504
__global__ __launch_bounds__(256) void prep_kernel(
    const u16* __restrict__ qkv, const float* __restrict__ cosf,
    const float* __restrict__ sinf, const float* __restrict__ Wo,
    u16* __restrict__ wob, u16* __restrict__ qb,
    u16* __restrict__ kb, u16* __restrict__ vbt)
{
  __shared__ u16 tile[64][66];     // used by vtrans branch only
  const int tid = threadIdx.x;

  if (blockIdx.x < 1024) {
    // ---- Wo conversion ----
    int i = blockIdx.x * 256 + tid;
    const int stride = 1024 * 256;
    for (; i < 1048576; i += stride)
      ((ushort4*)wob)[i] = cvt4(((const float4*)Wo)[i]);
  } else if (blockIdx.x < 5120) {
    // ---- RoPE ----
    const int bt = blockIdx.x - 1024;
    const int b = bt / T_SEQ, t = bt % T_SEQ;
    const u16* row = qkv + (size_t)bt * QKV_W;

    #pragma unroll
    for (int i = 0; i < 4; i++) {
      int idx = i * 256 + tid;          // 0..1023
      int h = idx >> 5, dp = idx & 31;
      float x1 = bf2f(row[h * 64 + dp]);
      float x2 = bf2f(row[h * 64 + dp + 32]);
      float c = cosf[t * 64 + dp];
      float s = sinf[t * 64 + dp];
      float o1 = (x1 * c - x2 * s) * QSCALE;
      float o2 = (x2 * c + x1 * s) * QSCALE;
      size_t base = ((size_t)(b * NH + h) * T_SEQ + t) * HD + dp;
      qb[base]      = f2bf(o1);
      qb[base + 32] = f2bf(o2);
    }
    {
      int idx = tid;                    // 0..255
      int kvh = idx >> 5, dp = idx & 31;
      float x1 = bf2f(row[2048 + kvh * 64 + dp]);
      float x2 = bf2f(row[2048 + kvh * 64 + dp + 32]);
      float c = cosf[t * 64 + dp];
      float s = sinf[t * 64 + dp];
      size_t base = ((size_t)(b * NKV + kvh) * T_SEQ + t) * HD + dp;
      kb[base]      = f2bf(x1 * c - x2 * s);
      kb[base + 32] = f2bf(x2 * c + x1 * s);
    }
  } else {
    // ---- V transpose: qkv cols [2560,3072) -> vbt (B,KV,64,T) ----
    const int idx2 = blockIdx.x - 5120;   // 0..511
    const int t0  = (idx2 & 31) * 64;
    const int kvh = (idx2 >> 5) & 7;
    const int b   = idx2 >> 8;

    #pragma unroll
    for (int i = 0; i < 16; i++) {
      int idx = i * 256 + tid;
      int r = idx >> 6, c = idx & 63;
      tile[r][c] = qkv[(size_t)(b * T_SEQ + t0 + r) * QKV_W + 2560 + kvh * 64 + c];
    }
    __syncthreads();
    #pragma unroll
    for (int i = 0; i < 16; i++) {
      int idx = i * 256 + tid;
      int d = idx >> 6, c = idx & 63;
      vbt[((size_t)(b * NKV + kvh) * HD + d) * T_SEQ + t0 + c] = tile[c][d];
    }
  }
}

// ---------------------------------------------------------------------------
// Flash attention v9 (GQA-fused, 32-row q-tiles, paired-tile staging,
// split-phase tile body). Two-barrier sync template (deterministic;
// single-barrier dbuf retired r6). launch_bounds(256,3); defer-max (THR=8,
// log2); setprio around MFMA; 1024-block descending LPT grid. LDS ~42 KB.
// ---------------------------------------------------------------------------
__global__ __launch_bounds__(256, 3) void attn_kernel(
    const u16* __restrict__ qb, const u16* __restrict__ kb,
    const u16* __restrict__ vbt, u16* __restrict__ attn)
{
  __shared__ __align__(16) u16 sK[2][64 * 64];  // 16 KB, chunk-swizzled
  __shared__ __align__(16) u16 sV[2][64 * 64];  // 16 KB, chunk-swizzled
  __shared__ __align__(16) u16 sP[4][16][72];   // per-wave P, A-layout
  __shared__ float sAl[4][16];                  // alpha / l transpose slot

  const int tid  = threadIdx.x;
  const int lane = tid & 63;
  const int w    = tid >> 6;

  // descending-length dispatch: qt = 63 first (longest), qt = 0 last
  const int l  = blockIdx.x;          // 0..1023
  const int qt = 63 - (l >> 4);       // 32-row q-tile index
  const int kv = l & 7;
  const int b  = (l >> 3) & 1;
  const int h  = kv * 4 + w;
  const int ktmax = qt >> 1;          // last 64-col k-tile index
  const int moff  = 32 * (qt & 1);    // diag-tile mask offset

  const int lm = lane & 15, lq = lane >> 4;
  const int sw = lm & 7;                          // XOR swizzle key

  // Q fragments (B-operand): qf[nq][c] covers q = qt*32+nq*16+lm, d = c*32+lq*8
  bf16x8 qf[2][2];
  {
    const u16* qhead = qb + ((size_t)(b * NH + h) * T_SEQ + qt * 32) * HD;
    #pragma unroll
    for (int nq = 0; nq < 2; nq++) {
      const u16* qrow = qhead + (size_t)(nq * 16 + lm) * HD + lq * 8;
      qf[nq][0] = *(const bf16x8*)(qrow);
      qf[nq][1] = *(const bf16x8*)(qrow + 32);
    }
  }

  floatx4 o_acc[2][4];
  #pragma unroll
  for (int i = 0; i < 2; i++)
    #pragma unroll
    for (int j = 0; j < 4; j++) { floatx4 z = {0.f,0.f,0.f,0.f}; o_acc[i][j] = z; }
  float m_run[2] = {-1e30f, -1e30f};
  float l_run[2] = {0.f, 0.f};

  const u16* kbase = kb  + (size_t)(b * NKV + kv) * T_SEQ * HD;
  const u16* vbase = vbt + (size_t)(b * NKV + kv) * HD * T_SEQ;

  // precomputed staging lane addresses
  const int p0row = tid >> 3,        p1row = (256 + tid) >> 3;
  const int p0ck  = (tid & 7) ^ (p0row & 7), p1ck = ((256 + tid) & 7) ^ (p1row & 7);
  const u16* kp0 = kbase + (size_t)p0row * HD + p0ck * 8;
  const u16* kp1 = kbase + (size_t)p1row * HD + p1ck * 8;
  const u16* vp0 = vbase + (size_t)p0row * T_SEQ + p0ck * 8;
  const u16* vp1 = vbase + (size_t)p1row * T_SEQ + p1ck * 8;
  const int d0 = tid * 16, d1 = (256 + tid) * 16;

  // per-tile compute body (split-phase)
  auto compute_tile = [&](const u16* sKc, const u16* sVc, const bool diag) {
    bf16x8 kf[4][2], vf[4][2];
    #pragma unroll
    for (int nt = 0; nt < 4; nt++) {
      kf[nt][0] = *(const bf16x8*)(sKc + (((nt*16 + lm) * 8 + (lq ^ sw)) << 3));
      kf[nt][1] = *(const bf16x8*)(sKc + (((nt*16 + lm) * 8 + ((4 + lq) ^ sw)) << 3));
      vf[nt][0] = *(const bf16x8*)(sVc + (((nt*16 + lm) * 8 + (lq ^ sw)) << 3));
      vf[nt][1] = *(const bf16x8*)(sVc + (((nt*16 + lm) * 8 + ((4 + lq) ^ sw)) << 3));
    }

    // ---- Phase 1: S^T for BOTH nq (16 MFMA back-to-back) ----
    floatx4 s_acc[2][4];
    __builtin_amdgcn_s_setprio(1);
    #pragma unroll
    for (int nq = 0; nq < 2; nq++)
      #pragma unroll
      for (int nt = 0; nt < 4; nt++) {
        floatx4 z = {0.f,0.f,0.f,0.f};
        z = __builtin_amdgcn_mfma_f32_16x16x32_bf16(kf[nt][0], qf[nq][0], z, 0, 0, 0);
        z = __builtin_amdgcn_mfma_f32_16x16x32_bf16(kf[nt][1], qf[nq][1], z, 0, 0, 0);
        s_acc[nq][nt] = z;
      }
    __builtin_amdgcn_s_setprio(0);

    // ---- Phase 2: per-nq mask + softmax + PV ----
    #pragma unroll
    for (int nq = 0; nq < 2; nq++) {
      if (diag) {   // diagonal tile: causal mask (k > q)
        #pragma unroll
        for (int nt = 0; nt < 4; nt++)
          #pragma unroll
          for (int r = 0; r < 4; r++)
            if (nt * 16 + lq * 4 + r > nq * 16 + lm + moff) s_acc[nq][nt][r] = -1e30f;
      }

      float mloc = s_acc[nq][0][0];
      #pragma unroll
      for (int nt = 0; nt < 4; nt++)
        #pragma unroll
        for (int r = 0; r < 4; r++) mloc = fmaxf(mloc, s_acc[nq][nt][r]);
      mloc = fmaxf(mloc, __shfl_xor(mloc, 16));
      mloc = fmaxf(mloc, __shfl_xor(mloc, 32));

      // defer-max: only rescale when the tile max outgrows m_run by >8
      float mnew = m_run[nq];
      if (!__all(mloc - m_run[nq] <= 8.0f)) {
        mnew = fmaxf(m_run[nq], mloc);
        float al = fexp2(m_run[nq] - mnew);
        m_run[nq] = mnew;
        l_run[nq] *= al;
        if (lq == 0) sAl[w][lm] = al;
        floatx4 alv = *(const floatx4*)&sAl[w][lq * 4];
        #pragma unroll
        for (int nd = 0; nd < 4; nd++)
          #pragma unroll
          for (int r = 0; r < 4; r++)
            o_acc[nq][nd][r] *= alv[r];
      }

      float rs = 0.f;
      uint2 pk[4];
      #pragma unroll
      for (int nt = 0; nt < 4; nt++) {
        float p0 = fexp2(s_acc[nq][nt][0] - mnew);
        float p1 = fexp2(s_acc[nq][nt][1] - mnew);
        float p2 = fexp2(s_acc[nq][nt][2] - mnew);
        float p3 = fexp2(s_acc[nq][nt][3] - mnew);
        rs += (p0 + p1) + (p2 + p3);
        pk[nt].x = pk2bf(p1, p0);
        pk[nt].y = pk2bf(p3, p2);
      }
      rs += __shfl_xor(rs, 16);
      rs += __shfl_xor(rs, 32);
      l_run[nq] += rs;

      #pragma unroll
      for (int nt = 0; nt < 4; nt++)
        *(uint2*)&sP[w][lm][nt * 16 + lq * 4] = pk[nt];

      __builtin_amdgcn_s_setprio(1);
      #pragma unroll
      for (int st = 0; st < 2; st++) {
        bf16x8 pf = *(const bf16x8*)(&sP[w][lm][st * 32 + lq * 8]);
        #pragma unroll
        for (int nd = 0; nd < 4; nd++)
          o_acc[nq][nd] = __builtin_amdgcn_mfma_f32_16x16x32_bf16(
              pf, vf[nd][st], o_acc[nq][nd], 0, 0, 0);
      }
      __builtin_amdgcn_s_setprio(0);
    }
  };

  const int nst = (ktmax >> 1) + 1;   // stages of two 64-col tiles
  for (int s2 = 0; s2 < nst; s2++) {
    const int kt0  = s2 * 2;
    const int kt1  = kt0 + 1;
    const int kt1c = kt1 < 32 ? kt1 : 31;   // clamp staging addr (valid mem)
    __syncthreads();   // prior stage's sK/sV reads complete
    gld_lds16(kp0 + (size_t)kt0  * 64 * HD, (char*)sK[0] + d0);
    gld_lds16(kp1 + (size_t)kt0  * 64 * HD, (char*)sK[0] + d1);
    gld_lds16(kp0 + (size_t)kt1c * 64 * HD, (char*)sK[1] + d0);
    gld_lds16(kp1 + (size_t)kt1c * 64 * HD, (char*)sK[1] + d1);
    gld_lds16(vp0 + kt0  * 64, (char*)sV[0] + d0);
    gld_lds16(vp1 + kt0  * 64, (char*)sV[0] + d1);
    gld_lds16(vp0 + kt1c * 64, (char*)sV[1] + d0);
    gld_lds16(vp1 + kt1c * 64, (char*)sV[1] + d1);
    __syncthreads();   // staging visible (auto vmcnt(0) drain before barrier)

    compute_tile(sK[0], sV[0], kt0 == ktmax);
    if (kt1 <= ktmax) compute_tile(sK[1], sV[1], kt1 == ktmax);
  }

  // ---- epilogue: per nq transpose l, normalize, store ----
  #pragma unroll
  for (int nq = 0; nq < 2; nq++) {
    __builtin_amdgcn_s_waitcnt(0);  // ensure prior sAl use complete (same wave)
    if (lq == 0) sAl[w][lm] = l_run[nq];
    floatx4 lv = *(const floatx4*)&sAl[w][lq * 4];
    #pragma unroll
    for (int nd = 0; nd < 4; nd++)
      #pragma unroll
      for (int r = 0; r < 4; r++) {
        float v = o_acc[nq][nd][r] / lv[r];
        size_t row = (size_t)b * T_SEQ + qt * 32 + nq * 16 + lq * 4 + r;
        attn[row * DM + h * HD + nd * 16 + lm] = f2bf(v);
      }
  }
}

// ---------------------------------------------------------------------------
extern "C" void kernel_launch(void* const* d_in, const int* in_sizes, int n_in,
                              void* d_out, int out_size, void* d_ws, size_t ws_size,
                              hipStream_t stream)
{
  const float* x    = (const float*)d_in[0];
  const float* cosf = (const float*)d_in[1];
  const float* sinf = (const float*)d_in[2];
  const float* Wq   = (const float*)d_in[3];
  const float* Wk   = (const float*)d_in[4];
  const float* Wv   = (const float*)d_in[5];
  const float* Wo   = (const float*)d_in[6];
  float* out = (float*)d_out;

  char* ws = (char*)d_ws;
  u16* qkvb  = (u16*)(ws + 0);          // 4096x3072 bf16 = 25,165,824
  u16* attnb = (u16*)(ws + 0);          // reuse after prep
  u16* qb    = (u16*)(ws + 25165824);   // 16,777,216
  u16* kb    = (u16*)(ws + 41943040);   //  4,194,304
  u16* vbt   = (u16*)(ws + 46137344);   //  4,194,304
  u16* xb    = (u16*)(ws + 50331648);   // 16,777,216 (dead after gemm_qkv)
  u16* wob   = (u16*)(ws + 50331648);   //  8,388,608 (overwrites xb)
  u16* wqkvb = (u16*)(ws + 67108864);   // 12,582,912

  dim3 blk(256);
  conv_in_kernel<<<dim3(3584), blk, 0, stream>>>(x, xb, Wq, Wk, Wv, wqkvb);

  gemm_qkv_kernel<<<dim3(24, 32), blk, 0, stream>>>(xb, wqkvb, qkvb);

  prep_kernel<<<dim3(5632), blk, 0, stream>>>(qkvb, cosf, sinf, Wo, wob,
                                              qb, kb, vbt);
  attn_kernel<<<dim3(1024), blk, 0, stream>>>(qb, kb, vbt, attnb);
  gemm_out_kernel<<<dim3(16, 32), blk, 0, stream>>>(attnb, wob, out);
}